// Round 16
// baseline (65.742 us; speedup 1.0000x reference)
//
#include <hip/hip_runtime.h>
#include <hip/hip_bf16.h>

constexpr int D_ = 8, H_ = 64, W_ = 64, C_ = 96;
constexpr int WC    = W_ * C_;            // 6144
constexpr int HWC   = H_ * W_ * C_;       // 393216
constexpr int BDHWC = 2 * D_ * HWC;       // 6291456
constexpr float SCALE = 0.10206207261596577f;  // (384/4)^-0.5

typedef __attribute__((ext_vector_type(4))) float f32x4;
typedef __attribute__((ext_vector_type(8))) short s16x8;

__device__ inline ushort f2bf(float x) {
  union { __hip_bfloat16 h; ushort u; } c;
  c.h = __float2bfloat16(x);
  return c.u;
}
__device__ inline float bf2f(ushort u) {
  union { float f; unsigned i; } c;
  c.i = ((unsigned)u) << 16;
  return c.f;
}
__device__ inline int xswz8(int bid, int nwg) {
  return (bid & 7) * (nwg >> 3) + (bid >> 3);
}

// ================= Kernel A: MFMA attention, half-P, 37.4KB LDS =================
// (unchanged — ~19 us, near stream floor)
constexpr int QSTR  = 40;
constexpr int PSTR  = 136;
constexpr int PSTR2 = 72;

template <bool WSOUT>
__global__ void __launch_bounds__(256, 4)
attn_mfma_kernel(const float* __restrict__ qkv, float* __restrict__ out,
                 ushort* __restrict__ ws) {
  __shared__ ushort sK[128 * QSTR];    // 10240 B
  __shared__ ushort sVt[32 * PSTR];    //  8704 B
  __shared__ ushort sP[128 * PSTR2];   // 18432 B

  const int t    = threadIdx.x;
  const int bid  = xswz8(blockIdx.x, 2048);
  const int head = bid & 3;
  const int nw   = bid >> 2;
  const int wq   = nw & 31;
  const int d    = (nw >> 5) & 7;
  const int b    = nw >> 8;
  const int hc   = head * 24;

  const float* qpl = qkv + (size_t)(b * 8 + d) * HWC;
  const float* kpl = qpl + BDHWC;
  const float* vpl = kpl + BDHWC;

  {
    const s16x8 Z = {0, 0, 0, 0, 0, 0, 0, 0};
    int row = t >> 1, col = 24 + (t & 1) * 8;
    *reinterpret_cast<s16x8*>(&sK[row * QSTR + col]) = Z;
    if (t < 136) *reinterpret_cast<s16x8*>(&sVt[24 * PSTR + t * 8]) = Z;
  }

  #pragma unroll
  for (int it = 0; it < 3; ++it) {
    int idx = t + it * 256;
    int tok = idx / 6, c4 = (idx - tok * 6) * 4;
    int g = (tok >> 1) * WC + (wq * 2 + (tok & 1)) * 96 + hc + c4;
    float4 kv = *reinterpret_cast<const float4*>(kpl + g);
    float4 vv = *reinterpret_cast<const float4*>(vpl + g);
    ushort4 kh = { f2bf(kv.x), f2bf(kv.y), f2bf(kv.z), f2bf(kv.w) };
    *reinterpret_cast<ushort4*>(&sK[tok * QSTR + c4]) = kh;
    sVt[(c4 + 0) * PSTR + tok] = f2bf(vv.x);
    sVt[(c4 + 1) * PSTR + tok] = f2bf(vv.y);
    sVt[(c4 + 2) * PSTR + tok] = f2bf(vv.z);
    sVt[(c4 + 3) * PSTR + tok] = f2bf(vv.w);
  }

  const int wv = t >> 6, lane = t & 63;
  const int lr = lane & 15;
  const int lg = lane >> 4;
  const int r0 = (2 * wv) * 16;
  const int r1 = (2 * wv + 1) * 16;

  s16x8 a0 = {0,0,0,0,0,0,0,0}, a1 = {0,0,0,0,0,0,0,0};
  if (lg < 3) {
    union { s16x8 v; ushort u[8]; } qa;
    int tok = r0 + lr;
    const float* qp = qpl + (tok >> 1) * WC + (wq * 2 + (tok & 1)) * 96 + hc + lg * 8;
    float4 x0 = *reinterpret_cast<const float4*>(qp);
    float4 x1 = *reinterpret_cast<const float4*>(qp + 4);
    qa.u[0] = f2bf(x0.x * SCALE); qa.u[1] = f2bf(x0.y * SCALE);
    qa.u[2] = f2bf(x0.z * SCALE); qa.u[3] = f2bf(x0.w * SCALE);
    qa.u[4] = f2bf(x1.x * SCALE); qa.u[5] = f2bf(x1.y * SCALE);
    qa.u[6] = f2bf(x1.z * SCALE); qa.u[7] = f2bf(x1.w * SCALE);
    a0 = qa.v;
    tok = r1 + lr;
    qp = qpl + (tok >> 1) * WC + (wq * 2 + (tok & 1)) * 96 + hc + lg * 8;
    x0 = *reinterpret_cast<const float4*>(qp);
    x1 = *reinterpret_cast<const float4*>(qp + 4);
    qa.u[0] = f2bf(x0.x * SCALE); qa.u[1] = f2bf(x0.y * SCALE);
    qa.u[2] = f2bf(x0.z * SCALE); qa.u[3] = f2bf(x0.w * SCALE);
    qa.u[4] = f2bf(x1.x * SCALE); qa.u[5] = f2bf(x1.y * SCALE);
    qa.u[6] = f2bf(x1.z * SCALE); qa.u[7] = f2bf(x1.w * SCALE);
    a1 = qa.v;
  }

  __syncthreads();

  float rsum[2][4];
  #pragma unroll
  for (int rb = 0; rb < 2; ++rb)
    #pragma unroll
    for (int r = 0; r < 4; ++r) rsum[rb][r] = 0.f;

  f32x4 accO[2][2];
  #pragma unroll
  for (int i = 0; i < 2; ++i)
    #pragma unroll
    for (int j = 0; j < 2; ++j) accO[i][j] = f32x4{0.f, 0.f, 0.f, 0.f};

  #pragma unroll
  for (int half = 0; half < 2; ++half) {
    f32x4 accS[2][4];
    #pragma unroll
    for (int i = 0; i < 2; ++i)
      #pragma unroll
      for (int j = 0; j < 4; ++j) accS[i][j] = f32x4{0.f, 0.f, 0.f, 0.f};

    #pragma unroll
    for (int nb = 0; nb < 4; ++nb) {
      s16x8 bb = *reinterpret_cast<const s16x8*>(
          &sK[(half * 64 + nb * 16 + lr) * QSTR + lg * 8]);
      accS[0][nb] = __builtin_amdgcn_mfma_f32_16x16x32_bf16(a0, bb, accS[0][nb], 0, 0, 0);
      accS[1][nb] = __builtin_amdgcn_mfma_f32_16x16x32_bf16(a1, bb, accS[1][nb], 0, 0, 0);
    }

    #pragma unroll
    for (int rb = 0; rb < 2; ++rb)
      #pragma unroll
      for (int nb = 0; nb < 4; ++nb)
        #pragma unroll
        for (int r = 0; r < 4; ++r) {
          float e = __expf(accS[rb][nb][r]);
          accS[rb][nb][r] = e;
          rsum[rb][r] += e;
        }

    if (half) __syncthreads();

    #pragma unroll
    for (int rb = 0; rb < 2; ++rb)
      #pragma unroll
      for (int nb = 0; nb < 4; ++nb)
        #pragma unroll
        for (int r = 0; r < 4; ++r)
          sP[((2 * wv + rb) * 16 + lg * 4 + r) * PSTR2 + nb * 16 + lr] =
              f2bf(accS[rb][nb][r]);
    __syncthreads();

    #pragma unroll
    for (int kb = 0; kb < 2; ++kb) {
      int kc = half * 64 + kb * 32 + lg * 8;
      s16x8 pa0 = *reinterpret_cast<const s16x8*>(&sP[(r0 + lr) * PSTR2 + kb * 32 + lg * 8]);
      s16x8 pa1 = *reinterpret_cast<const s16x8*>(&sP[(r1 + lr) * PSTR2 + kb * 32 + lg * 8]);
      s16x8 vb0 = *reinterpret_cast<const s16x8*>(&sVt[lr * PSTR + kc]);
      s16x8 vb1 = *reinterpret_cast<const s16x8*>(&sVt[(16 + lr) * PSTR + kc]);
      accO[0][0] = __builtin_amdgcn_mfma_f32_16x16x32_bf16(pa0, vb0, accO[0][0], 0, 0, 0);
      accO[0][1] = __builtin_amdgcn_mfma_f32_16x16x32_bf16(pa0, vb1, accO[0][1], 0, 0, 0);
      accO[1][0] = __builtin_amdgcn_mfma_f32_16x16x32_bf16(pa1, vb0, accO[1][0], 0, 0, 0);
      accO[1][1] = __builtin_amdgcn_mfma_f32_16x16x32_bf16(pa1, vb1, accO[1][1], 0, 0, 0);
    }
  }

  float* opl   = out + (size_t)(b * 8 + d) * HWC;
  ushort* wpl  = ws  + (size_t)(b * 8 + d) * HWC;
  #pragma unroll
  for (int rb = 0; rb < 2; ++rb) {
    #pragma unroll
    for (int r = 0; r < 4; ++r) {
      float s = rsum[rb][r];
      s += __shfl_xor(s, 1); s += __shfl_xor(s, 2);
      s += __shfl_xor(s, 4); s += __shfl_xor(s, 8);
      int tok = (2 * wv + rb) * 16 + lg * 4 + r;
      int g = (tok >> 1) * WC + (wq * 2 + (tok & 1)) * 96 + hc;
      float inv = 1.0f / s;
      if (WSOUT) {
        wpl[g + lr] = f2bf(accO[rb][0][r] * inv);
        if (lr < 8) wpl[g + 16 + lr] = f2bf(accO[rb][1][r] * inv);
      } else {
        opl[g + lr] = accO[rb][0][r] * inv;
        if (lr < 8) opl[g + 16 + lr] = accO[rb][1][r] * inv;
      }
    }
  }
}

// ====== Kernel CB: fused LePE + MFMA proj — rotated-region de-phasing ======
// Same r11 resources (39.4KB LDS, 4 blocks/CU) but each block walks the 9
// stencil regions in rotated order (off = blockIdx%9): co-resident blocks
// stall on staging at DIFFERENT phases -> cross-block TLP covers the stalls.
// Rolled loop (#pragma unroll 1) + runtime region index: loads can't be
// hoisted across barriers (the r12-r14 spill trigger).
constexpr int VSTR = 104;
constexpr int WSTR = 104;

template <bool WSIN>
__global__ void __launch_bounds__(256, 4)
lepe_proj_fused_kernel(const float* __restrict__ qkv, const float* __restrict__ cw,
                       const float* __restrict__ cbias, const float* __restrict__ pw,
                       const float* __restrict__ pb, float* __restrict__ io,
                       const ushort* __restrict__ ws) {
  __shared__ ushort sV[64 * VSTR];    // 13312 B
  __shared__ ushort sW[96 * WSTR];    // 19968 B
  __shared__ ushort sCW[27 * 96];     //  5184 B
  __shared__ float  sCB[96];
  __shared__ float  sPB[96];

  const int t   = threadIdx.x;
  const int rawbid = blockIdx.x;
  const int bid = xswz8(rawbid, 1024);
  const int h   = bid & 63;
  const int d   = (bid >> 6) & 7;
  const int b   = bid >> 9;

  float* iop = io + (size_t)(b * 8 + d) * HWC + h * WC;
  const ushort* wsp = ws + (size_t)(b * 8 + d) * HWC + h * WC;
  const float* vbatch = qkv + 2 * (size_t)BDHWC + (size_t)b * 8 * HWC;

  const int tt  = t >> 2;
  const int cbk = (t & 3) * 24;

  // ---- attn rows: issue reads first (in flight under weight staging) ----
  float lep[24];
  if (WSIN) {
    union { s16x8 v; ushort u[8]; } azu[3];
    #pragma unroll
    for (int k = 0; k < 3; ++k)
      azu[k].v = *reinterpret_cast<const s16x8*>(wsp + tt * 96 + cbk + k * 8);
    #pragma unroll
    for (int k = 0; k < 3; ++k)
      #pragma unroll
      for (int e = 0; e < 8; ++e) lep[8*k+e] = bf2f(azu[k].u[e]);
  } else {
    float4 az[6];
    #pragma unroll
    for (int j = 0; j < 6; ++j)
      az[j] = *reinterpret_cast<const float4*>(iop + tt * 96 + cbk + j * 4);
    #pragma unroll
    for (int j = 0; j < 6; ++j) {
      lep[4*j+0] = az[j].x; lep[4*j+1] = az[j].y;
      lep[4*j+2] = az[j].z; lep[4*j+3] = az[j].w;
    }
  }

  // ---- stage weights ----
  #pragma unroll
  for (int it = 0; it < 9; ++it) {
    int idx = t + it * 256;
    int co = idx / 24, c4 = (idx - co * 24) * 4;
    float4 x = *reinterpret_cast<const float4*>(pw + co * 96 + c4);
    ushort4 hx = { f2bf(x.x), f2bf(x.y), f2bf(x.z), f2bf(x.w) };
    *reinterpret_cast<ushort4*>(&sW[co * WSTR + c4]) = hx;
  }
  for (int idx = t; idx < 2592; idx += 256) {
    int c = idx / 27, tap = idx - c * 27;
    sCW[tap * 96 + c] = f2bf(cw[idx]);
  }
  if (t < 96) { sCB[t] = cbias[t]; sPB[t] = pb[t]; }

  // ---- clamped region coords & validity factors (block-uniform) ----
  int   zdc[3], zhc[3];
  float fdc[3], fhc[3];
  #pragma unroll
  for (int j = 0; j < 3; ++j) {
    int zd = d + j - 1;
    fdc[j] = (zd >= 0 && zd < D_) ? 1.f : 0.f;
    zdc[j] = zd < 0 ? 0 : (zd > D_ - 1 ? D_ - 1 : zd);
    int zh = h + j - 1;
    fhc[j] = (zh >= 0 && zh < H_) ? 1.f : 0.f;
    zhc[j] = zh < 0 ? 0 : (zh > H_ - 1 ? H_ - 1 : zh);
  }
  const float fwl0 = (tt > 0)  ? 1.f : 0.f;
  const float fwl2 = (tt < 63) ? 1.f : 0.f;
  const int   zw0  = (tt > 0)  ? tt - 1 : 0;
  const int   zw2  = (tt < 63) ? tt + 1 : 63;

  #define TAP(zw, tap, FW)                                                   \
    {                                                                        \
      _Pragma("unroll")                                                      \
      for (int j8 = 0; j8 < 3; ++j8) {                                       \
        union { s16x8 v; ushort u[8]; } vu;                                  \
        vu.v = *reinterpret_cast<const s16x8*>(&sV[(zw) * VSTR + cbk + j8 * 8]); \
        union { s16x8 v; ushort u[8]; } wu;                                  \
        wu.v = *reinterpret_cast<const s16x8*>(&sCW[(tap) * 96 + cbk + j8 * 8]); \
        _Pragma("unroll")                                                    \
        for (int e = 0; e < 8; ++e)                                          \
          lep[8*j8+e] = fmaf(bf2f(vu.u[e]) * (FW), bf2f(wu.u[e]), lep[8*j8+e]); \
      }                                                                      \
    }

  // rotated region order: r = (rr + off) % 9, off differs across blocks
  const int off = rawbid % 9;

  #pragma unroll 1
  for (int rr = 0; rr < 9; ++rr) {
    int r = rr + off;
    if (r >= 9) r -= 9;
    const int dd = r / 3, dh = r - 3 * (r / 3);

    __syncthreads();   // previous taps done reading sV
    {
      const float4* src = reinterpret_cast<const float4*>(
          vbatch + (size_t)zdc[dd] * HWC + zhc[dh] * WC);
      #pragma unroll
      for (int it = 0; it < 6; ++it) {
        int idx = t + it * 256;
        int tok = idx / 24, c4 = idx - tok * 24;
        float4 x = src[idx];
        ushort4 hx = { f2bf(x.x), f2bf(x.y), f2bf(x.z), f2bf(x.w) };
        *reinterpret_cast<ushort4*>(&sV[tok * VSTR + c4 * 4]) = hx;
      }
    }
    __syncthreads();   // sV ready

    const float fr = fdc[dd] * fhc[dh];
    const int tap0 = r * 3;
    TAP(zw0, tap0 + 0, fr * fwl0);
    TAP(tt,  tap0 + 1, fr);
    TAP(zw2, tap0 + 2, fr * fwl2);
  }
  #undef TAP

  // ---- sV dead: repack (lep + conv bias) bf16 as proj input ----
  __syncthreads();
  #pragma unroll
  for (int j = 0; j < 6; ++j) {
    float4 bz = *reinterpret_cast<const float4*>(sCB + cbk + j * 4);
    ushort4 hx = { f2bf(lep[4*j+0] + bz.x), f2bf(lep[4*j+1] + bz.y),
                   f2bf(lep[4*j+2] + bz.z), f2bf(lep[4*j+3] + bz.w) };
    *reinterpret_cast<ushort4*>(&sV[tt * VSTR + cbk + j * 4]) = hx;
  }
  __syncthreads();

  const int wv = t >> 6, lane = t & 63;
  const int lr = lane & 15, lg = lane >> 4;

  f32x4 acc[6];
  #pragma unroll
  for (int cb = 0; cb < 6; ++cb) {
    float bv = sPB[cb * 16 + lr];
    acc[cb] = f32x4{bv, bv, bv, bv};
  }
  s16x8 afr[3];
  #pragma unroll
  for (int kb = 0; kb < 3; ++kb)
    afr[kb] = *reinterpret_cast<const s16x8*>(&sV[(wv * 16 + lr) * VSTR + kb * 32 + lg * 8]);
  #pragma unroll
  for (int kb = 0; kb < 3; ++kb) {
    #pragma unroll
    for (int cb = 0; cb < 6; ++cb) {
      s16x8 bfr = *reinterpret_cast<const s16x8*>(&sW[(cb * 16 + lr) * WSTR + kb * 32 + lg * 8]);
      acc[cb] = __builtin_amdgcn_mfma_f32_16x16x32_bf16(afr[kb], bfr, acc[cb], 0, 0, 0);
    }
  }

  #pragma unroll
  for (int cb = 0; cb < 6; ++cb) {
    #pragma unroll
    for (int r = 0; r < 4; ++r) {
      int tok = wv * 16 + lg * 4 + r;
      iop[tok * 96 + cb * 16 + lr] = acc[cb][r];
    }
  }
}

extern "C" void kernel_launch(void* const* d_in, const int* in_sizes, int n_in,
                              void* d_out, int out_size, void* d_ws, size_t ws_size,
                              hipStream_t stream) {
  const float* qkv = (const float*)d_in[0];
  const float* cw  = (const float*)d_in[1];
  const float* cb  = (const float*)d_in[2];
  const float* pw  = (const float*)d_in[3];
  const float* pb  = (const float*)d_in[4];
  float* out = (float*)d_out;
  ushort* ws = (ushort*)d_ws;

  const size_t need = (size_t)2 * D_ * HWC * sizeof(ushort);  // 12.6 MB
  if (ws_size >= need) {
    hipLaunchKernelGGL((attn_mfma_kernel<true>), dim3(2048), dim3(256), 0, stream,
                       qkv, out, ws);
    hipLaunchKernelGGL((lepe_proj_fused_kernel<true>), dim3(1024), dim3(256), 0, stream,
                       qkv, cw, cb, pw, pb, out, ws);
  } else {
    hipLaunchKernelGGL((attn_mfma_kernel<false>), dim3(2048), dim3(256), 0, stream,
                       qkv, out, ws);
    hipLaunchKernelGGL((lepe_proj_fused_kernel<false>), dim3(1024), dim3(256), 0, stream,
                       qkv, cw, cb, pw, pb, out, ws);
  }
}

// Round 17
// 56.878 us; speedup vs baseline: 1.1558x; 1.1558x over previous
//
#include <hip/hip_runtime.h>
#include <hip/hip_bf16.h>

constexpr int D_ = 8, H_ = 64, W_ = 64, C_ = 96;
constexpr int WC    = W_ * C_;            // 6144
constexpr int HWC   = H_ * W_ * C_;       // 393216
constexpr int BDHWC = 2 * D_ * HWC;       // 6291456 (elements per tensor)
constexpr float SCALE = 0.10206207261596577f;  // (384/4)^-0.5

typedef __attribute__((ext_vector_type(4))) float f32x4;
typedef __attribute__((ext_vector_type(8))) short s16x8;

__device__ inline ushort f2bf(float x) {
  union { __hip_bfloat16 h; ushort u; } c;
  c.h = __float2bfloat16(x);
  return c.u;
}
__device__ inline float bf2f(ushort u) {
  union { float f; unsigned i; } c;
  c.i = ((unsigned)u) << 16;
  return c.f;
}
__device__ inline int xswz8(int bid, int nwg) {
  return (bid & 7) * (nwg >> 3) + (bid >> 3);
}

// ================= Kernel A: MFMA attention, half-P, 37.4KB LDS =================
// WSOUT=1: attn rows bf16 -> ws[0..BDHWC); V bf16 -> ws[BDHWC..2*BDHWC).
constexpr int QSTR  = 40;
constexpr int PSTR  = 136;
constexpr int PSTR2 = 72;

template <bool WSOUT>
__global__ void __launch_bounds__(256, 4)
attn_mfma_kernel(const float* __restrict__ qkv, float* __restrict__ out,
                 ushort* __restrict__ ws) {
  __shared__ ushort sK[128 * QSTR];    // 10240 B
  __shared__ ushort sVt[32 * PSTR];    //  8704 B
  __shared__ ushort sP[128 * PSTR2];   // 18432 B

  const int t    = threadIdx.x;
  const int bid  = xswz8(blockIdx.x, 2048);
  const int head = bid & 3;
  const int nw   = bid >> 2;
  const int wq   = nw & 31;
  const int d    = (nw >> 5) & 7;
  const int b    = nw >> 8;
  const int hc   = head * 24;

  const float* qpl = qkv + (size_t)(b * 8 + d) * HWC;
  const float* kpl = qpl + BDHWC;
  const float* vpl = kpl + BDHWC;
  ushort* wvpl = ws + BDHWC + (size_t)(b * 8 + d) * HWC;   // V bf16 out

  {
    const s16x8 Z = {0, 0, 0, 0, 0, 0, 0, 0};
    int row = t >> 1, col = 24 + (t & 1) * 8;
    *reinterpret_cast<s16x8*>(&sK[row * QSTR + col]) = Z;
    if (t < 136) *reinterpret_cast<s16x8*>(&sVt[24 * PSTR + t * 8]) = Z;
  }

  #pragma unroll
  for (int it = 0; it < 3; ++it) {
    int idx = t + it * 256;
    int tok = idx / 6, c4 = (idx - tok * 6) * 4;
    int g = (tok >> 1) * WC + (wq * 2 + (tok & 1)) * 96 + hc + c4;
    float4 kv = *reinterpret_cast<const float4*>(kpl + g);
    float4 vv = *reinterpret_cast<const float4*>(vpl + g);
    ushort4 kh = { f2bf(kv.x), f2bf(kv.y), f2bf(kv.z), f2bf(kv.w) };
    ushort4 vh = { f2bf(vv.x), f2bf(vv.y), f2bf(vv.z), f2bf(vv.w) };
    *reinterpret_cast<ushort4*>(&sK[tok * QSTR + c4]) = kh;
    sVt[(c4 + 0) * PSTR + tok] = vh.x;
    sVt[(c4 + 1) * PSTR + tok] = vh.y;
    sVt[(c4 + 2) * PSTR + tok] = vh.z;
    sVt[(c4 + 3) * PSTR + tok] = vh.w;
    if (WSOUT) *reinterpret_cast<ushort4*>(wvpl + g) = vh;   // V bf16 handoff
  }

  const int wv = t >> 6, lane = t & 63;
  const int lr = lane & 15;
  const int lg = lane >> 4;
  const int r0 = (2 * wv) * 16;
  const int r1 = (2 * wv + 1) * 16;

  s16x8 a0 = {0,0,0,0,0,0,0,0}, a1 = {0,0,0,0,0,0,0,0};
  if (lg < 3) {
    union { s16x8 v; ushort u[8]; } qa;
    int tok = r0 + lr;
    const float* qp = qpl + (tok >> 1) * WC + (wq * 2 + (tok & 1)) * 96 + hc + lg * 8;
    float4 x0 = *reinterpret_cast<const float4*>(qp);
    float4 x1 = *reinterpret_cast<const float4*>(qp + 4);
    qa.u[0] = f2bf(x0.x * SCALE); qa.u[1] = f2bf(x0.y * SCALE);
    qa.u[2] = f2bf(x0.z * SCALE); qa.u[3] = f2bf(x0.w * SCALE);
    qa.u[4] = f2bf(x1.x * SCALE); qa.u[5] = f2bf(x1.y * SCALE);
    qa.u[6] = f2bf(x1.z * SCALE); qa.u[7] = f2bf(x1.w * SCALE);
    a0 = qa.v;
    tok = r1 + lr;
    qp = qpl + (tok >> 1) * WC + (wq * 2 + (tok & 1)) * 96 + hc + lg * 8;
    x0 = *reinterpret_cast<const float4*>(qp);
    x1 = *reinterpret_cast<const float4*>(qp + 4);
    qa.u[0] = f2bf(x0.x * SCALE); qa.u[1] = f2bf(x0.y * SCALE);
    qa.u[2] = f2bf(x0.z * SCALE); qa.u[3] = f2bf(x0.w * SCALE);
    qa.u[4] = f2bf(x1.x * SCALE); qa.u[5] = f2bf(x1.y * SCALE);
    qa.u[6] = f2bf(x1.z * SCALE); qa.u[7] = f2bf(x1.w * SCALE);
    a1 = qa.v;
  }

  __syncthreads();

  float rsum[2][4];
  #pragma unroll
  for (int rb = 0; rb < 2; ++rb)
    #pragma unroll
    for (int r = 0; r < 4; ++r) rsum[rb][r] = 0.f;

  f32x4 accO[2][2];
  #pragma unroll
  for (int i = 0; i < 2; ++i)
    #pragma unroll
    for (int j = 0; j < 2; ++j) accO[i][j] = f32x4{0.f, 0.f, 0.f, 0.f};

  #pragma unroll
  for (int half = 0; half < 2; ++half) {
    f32x4 accS[2][4];
    #pragma unroll
    for (int i = 0; i < 2; ++i)
      #pragma unroll
      for (int j = 0; j < 4; ++j) accS[i][j] = f32x4{0.f, 0.f, 0.f, 0.f};

    #pragma unroll
    for (int nb = 0; nb < 4; ++nb) {
      s16x8 bb = *reinterpret_cast<const s16x8*>(
          &sK[(half * 64 + nb * 16 + lr) * QSTR + lg * 8]);
      accS[0][nb] = __builtin_amdgcn_mfma_f32_16x16x32_bf16(a0, bb, accS[0][nb], 0, 0, 0);
      accS[1][nb] = __builtin_amdgcn_mfma_f32_16x16x32_bf16(a1, bb, accS[1][nb], 0, 0, 0);
    }

    #pragma unroll
    for (int rb = 0; rb < 2; ++rb)
      #pragma unroll
      for (int nb = 0; nb < 4; ++nb)
        #pragma unroll
        for (int r = 0; r < 4; ++r) {
          float e = __expf(accS[rb][nb][r]);
          accS[rb][nb][r] = e;
          rsum[rb][r] += e;
        }

    if (half) __syncthreads();

    #pragma unroll
    for (int rb = 0; rb < 2; ++rb)
      #pragma unroll
      for (int nb = 0; nb < 4; ++nb)
        #pragma unroll
        for (int r = 0; r < 4; ++r)
          sP[((2 * wv + rb) * 16 + lg * 4 + r) * PSTR2 + nb * 16 + lr] =
              f2bf(accS[rb][nb][r]);
    __syncthreads();

    #pragma unroll
    for (int kb = 0; kb < 2; ++kb) {
      int kc = half * 64 + kb * 32 + lg * 8;
      s16x8 pa0 = *reinterpret_cast<const s16x8*>(&sP[(r0 + lr) * PSTR2 + kb * 32 + lg * 8]);
      s16x8 pa1 = *reinterpret_cast<const s16x8*>(&sP[(r1 + lr) * PSTR2 + kb * 32 + lg * 8]);
      s16x8 vb0 = *reinterpret_cast<const s16x8*>(&sVt[lr * PSTR + kc]);
      s16x8 vb1 = *reinterpret_cast<const s16x8*>(&sVt[(16 + lr) * PSTR + kc]);
      accO[0][0] = __builtin_amdgcn_mfma_f32_16x16x32_bf16(pa0, vb0, accO[0][0], 0, 0, 0);
      accO[0][1] = __builtin_amdgcn_mfma_f32_16x16x32_bf16(pa0, vb1, accO[0][1], 0, 0, 0);
      accO[1][0] = __builtin_amdgcn_mfma_f32_16x16x32_bf16(pa1, vb0, accO[1][0], 0, 0, 0);
      accO[1][1] = __builtin_amdgcn_mfma_f32_16x16x32_bf16(pa1, vb1, accO[1][1], 0, 0, 0);
    }
  }

  float* opl   = out + (size_t)(b * 8 + d) * HWC;
  ushort* wpl  = ws  + (size_t)(b * 8 + d) * HWC;
  #pragma unroll
  for (int rb = 0; rb < 2; ++rb) {
    #pragma unroll
    for (int r = 0; r < 4; ++r) {
      float s = rsum[rb][r];
      s += __shfl_xor(s, 1); s += __shfl_xor(s, 2);
      s += __shfl_xor(s, 4); s += __shfl_xor(s, 8);
      int tok = (2 * wv + rb) * 16 + lg * 4 + r;
      int g = (tok >> 1) * WC + (wq * 2 + (tok & 1)) * 96 + hc;
      float inv = 1.0f / s;
      if (WSOUT) {
        wpl[g + lr] = f2bf(accO[rb][0][r] * inv);
        if (lr < 8) wpl[g + 16 + lr] = f2bf(accO[rb][1][r] * inv);
      } else {
        opl[g + lr] = accO[rb][0][r] * inv;
        if (lr < 8) opl[g + 16 + lr] = accO[rb][1][r] * inv;
      }
    }
  }
}

// ====== Kernel CB: fused LePE + MFMA proj — r15 structure, bf16-V staging ======
// WSIN=1: attn rows AND V read as bf16 from ws (staging = pure u16x8 copy,
// no f2bf). CFG identical to r15 (continue-guarded unrolled regions).
constexpr int VSTR = 104;
constexpr int WSTR = 104;

template <bool WSIN>
__global__ void __launch_bounds__(256, 4)
lepe_proj_fused_kernel(const float* __restrict__ qkv, const float* __restrict__ cw,
                       const float* __restrict__ cbias, const float* __restrict__ pw,
                       const float* __restrict__ pb, float* __restrict__ io,
                       const ushort* __restrict__ ws) {
  __shared__ ushort sV[64 * VSTR];    // 13312 B
  __shared__ ushort sW[96 * WSTR];    // 19968 B
  __shared__ ushort sCW[27 * 96];     //  5184 B
  __shared__ float  sCB[96];
  __shared__ float  sPB[96];

  const int t   = threadIdx.x;
  const int bid = xswz8(blockIdx.x, 1024);
  const int h   = bid & 63;
  const int d   = (bid >> 6) & 7;
  const int b   = bid >> 9;

  float* iop = io + (size_t)(b * 8 + d) * HWC + h * WC;
  const ushort* wsp = ws + (size_t)(b * 8 + d) * HWC + h * WC;       // attn rows
  const ushort* wvb = ws + BDHWC + (size_t)b * 8 * HWC;              // V bf16 batch
  const float* vbatch = qkv + 2 * (size_t)BDHWC + (size_t)b * 8 * HWC;

  const int tt  = t >> 2;
  const int cbk = (t & 3) * 24;

  // ---- attn rows: issue reads first (in flight under weight staging) ----
  float lep[24];
  if (WSIN) {
    union { s16x8 v; ushort u[8]; } azu[3];
    #pragma unroll
    for (int k = 0; k < 3; ++k)
      azu[k].v = *reinterpret_cast<const s16x8*>(wsp + tt * 96 + cbk + k * 8);
    #pragma unroll
    for (int k = 0; k < 3; ++k)
      #pragma unroll
      for (int e = 0; e < 8; ++e) lep[8*k+e] = bf2f(azu[k].u[e]);
  } else {
    float4 az[6];
    #pragma unroll
    for (int j = 0; j < 6; ++j)
      az[j] = *reinterpret_cast<const float4*>(iop + tt * 96 + cbk + j * 4);
    #pragma unroll
    for (int j = 0; j < 6; ++j) {
      lep[4*j+0] = az[j].x; lep[4*j+1] = az[j].y;
      lep[4*j+2] = az[j].z; lep[4*j+3] = az[j].w;
    }
  }

  // ---- stage weights ----
  #pragma unroll
  for (int it = 0; it < 9; ++it) {
    int idx = t + it * 256;
    int co = idx / 24, c4 = (idx - co * 24) * 4;
    float4 x = *reinterpret_cast<const float4*>(pw + co * 96 + c4);
    ushort4 hx = { f2bf(x.x), f2bf(x.y), f2bf(x.z), f2bf(x.w) };
    *reinterpret_cast<ushort4*>(&sW[co * WSTR + c4]) = hx;
  }
  for (int idx = t; idx < 2592; idx += 256) {
    int c = idx / 27, tap = idx - c * 27;
    sCW[tap * 96 + c] = f2bf(cw[idx]);
  }
  if (t < 96) { sCB[t] = cbias[t]; sPB[t] = pb[t]; }

  const float fw0 = (tt > 0)  ? 1.f : 0.f;
  const float fw2 = (tt < 63) ? 1.f : 0.f;
  const int   zw0 = (tt > 0)  ? tt - 1 : 0;
  const int   zw2 = (tt < 63) ? tt + 1 : 63;

  #define TAP(zw, tap, FW)                                                   \
    {                                                                        \
      _Pragma("unroll")                                                      \
      for (int j8 = 0; j8 < 3; ++j8) {                                       \
        union { s16x8 v; ushort u[8]; } vu;                                  \
        vu.v = *reinterpret_cast<const s16x8*>(&sV[(zw) * VSTR + cbk + j8 * 8]); \
        union { s16x8 v; ushort u[8]; } wu;                                  \
        wu.v = *reinterpret_cast<const s16x8*>(&sCW[(tap) * 96 + cbk + j8 * 8]); \
        _Pragma("unroll")                                                    \
        for (int e = 0; e < 8; ++e)                                          \
          lep[8*j8+e] = fmaf(bf2f(vu.u[e]) * (FW), bf2f(wu.u[e]), lep[8*j8+e]); \
      }                                                                      \
    }

  #pragma unroll
  for (int dd = 0; dd < 3; ++dd) {
    int zd = d + dd - 1;
    if (zd < 0 || zd >= D_) continue;        // block-uniform
    #pragma unroll
    for (int dh = 0; dh < 3; ++dh) {
      int zh = h + dh - 1;
      if (zh < 0 || zh >= H_) continue;      // block-uniform
      __syncthreads();   // previous sV fully consumed
      if (WSIN) {
        // pure bf16 copy: 768 u16x8 chunks, no conversion
        const ushort* vrow = wvb + (size_t)zd * HWC + zh * WC;
        #pragma unroll
        for (int it = 0; it < 3; ++it) {
          int idx = t + it * 256;
          int tok = idx / 12, c8 = idx - tok * 12;
          s16x8 x = *reinterpret_cast<const s16x8*>(vrow + tok * 96 + c8 * 8);
          *reinterpret_cast<s16x8*>(&sV[tok * VSTR + c8 * 8]) = x;
        }
      } else {
        const float4* src = reinterpret_cast<const float4*>(
            vbatch + (size_t)zd * HWC + zh * WC);
        #pragma unroll
        for (int it = 0; it < 6; ++it) {
          int idx = t + it * 256;
          int tok = idx / 24, c4 = idx - tok * 24;
          float4 x = src[idx];
          ushort4 hx = { f2bf(x.x), f2bf(x.y), f2bf(x.z), f2bf(x.w) };
          *reinterpret_cast<ushort4*>(&sV[tok * VSTR + c4 * 4]) = hx;
        }
      }
      __syncthreads();
      const int tap0 = dd * 9 + dh * 3;
      TAP(zw0, tap0 + 0, fw0);
      TAP(tt,  tap0 + 1, 1.f);
      TAP(zw2, tap0 + 2, fw2);
    }
  }
  #undef TAP

  // ---- sV dead: repack (lep + conv bias) bf16 as proj input ----
  __syncthreads();
  #pragma unroll
  for (int j = 0; j < 6; ++j) {
    float4 bz = *reinterpret_cast<const float4*>(sCB + cbk + j * 4);
    ushort4 hx = { f2bf(lep[4*j+0] + bz.x), f2bf(lep[4*j+1] + bz.y),
                   f2bf(lep[4*j+2] + bz.z), f2bf(lep[4*j+3] + bz.w) };
    *reinterpret_cast<ushort4*>(&sV[tt * VSTR + cbk + j * 4]) = hx;
  }
  __syncthreads();

  const int wv = t >> 6, lane = t & 63;
  const int lr = lane & 15, lg = lane >> 4;

  f32x4 acc[6];
  #pragma unroll
  for (int cb = 0; cb < 6; ++cb) {
    float bv = sPB[cb * 16 + lr];
    acc[cb] = f32x4{bv, bv, bv, bv};
  }
  s16x8 afr[3];
  #pragma unroll
  for (int kb = 0; kb < 3; ++kb)
    afr[kb] = *reinterpret_cast<const s16x8*>(&sV[(wv * 16 + lr) * VSTR + kb * 32 + lg * 8]);
  #pragma unroll
  for (int kb = 0; kb < 3; ++kb) {
    #pragma unroll
    for (int cb = 0; cb < 6; ++cb) {
      s16x8 bfr = *reinterpret_cast<const s16x8*>(&sW[(cb * 16 + lr) * WSTR + kb * 32 + lg * 8]);
      acc[cb] = __builtin_amdgcn_mfma_f32_16x16x32_bf16(afr[kb], bfr, acc[cb], 0, 0, 0);
    }
  }

  #pragma unroll
  for (int cb = 0; cb < 6; ++cb) {
    #pragma unroll
    for (int r = 0; r < 4; ++r) {
      int tok = wv * 16 + lg * 4 + r;
      iop[tok * 96 + cb * 16 + lr] = acc[cb][r];
    }
  }
}

extern "C" void kernel_launch(void* const* d_in, const int* in_sizes, int n_in,
                              void* d_out, int out_size, void* d_ws, size_t ws_size,
                              hipStream_t stream) {
  const float* qkv = (const float*)d_in[0];
  const float* cw  = (const float*)d_in[1];
  const float* cb  = (const float*)d_in[2];
  const float* pw  = (const float*)d_in[3];
  const float* pb  = (const float*)d_in[4];
  float* out = (float*)d_out;
  ushort* ws = (ushort*)d_ws;

  const size_t need = (size_t)2 * BDHWC * sizeof(ushort);  // 25.2 MB
  if (ws_size >= need) {
    hipLaunchKernelGGL((attn_mfma_kernel<true>), dim3(2048), dim3(256), 0, stream,
                       qkv, out, ws);
    hipLaunchKernelGGL((lepe_proj_fused_kernel<true>), dim3(1024), dim3(256), 0, stream,
                       qkv, cw, cb, pw, pb, out, ws);
  } else {
    hipLaunchKernelGGL((attn_mfma_kernel<false>), dim3(2048), dim3(256), 0, stream,
                       qkv, out, ws);
    hipLaunchKernelGGL((lepe_proj_fused_kernel<false>), dim3(1024), dim3(256), 0, stream,
                       qkv, cw, cb, pw, pb, out, ws);
  }
}

// Round 18
// 56.614 us; speedup vs baseline: 1.1612x; 1.0047x over previous
//
#include <hip/hip_runtime.h>
#include <hip/hip_bf16.h>

constexpr int D_ = 8, H_ = 64, W_ = 64, C_ = 96;
constexpr int WC    = W_ * C_;            // 6144
constexpr int HWC   = H_ * W_ * C_;       // 393216
constexpr int BDHWC = 2 * D_ * HWC;       // 6291456 (elements per tensor)
constexpr float SCALE = 0.10206207261596577f;  // (384/4)^-0.5

typedef __attribute__((ext_vector_type(4))) float f32x4;
typedef __attribute__((ext_vector_type(8))) short s16x8;

__device__ inline ushort f2bf(float x) {
  union { __hip_bfloat16 h; ushort u; } c;
  c.h = __float2bfloat16(x);
  return c.u;
}
__device__ inline float bf2f(ushort u) {
  union { float f; unsigned i; } c;
  c.i = ((unsigned)u) << 16;
  return c.f;
}
__device__ inline int xswz8(int bid, int nwg) {
  return (bid & 7) * (nwg >> 3) + (bid >> 3);
}

// ================= Kernel A: MFMA attention, half-P, 37.4KB LDS =================
// WSOUT=1: attn rows bf16 -> ws[0..BDHWC); V bf16 -> ws[BDHWC..2*BDHWC).
constexpr int QSTR  = 40;
constexpr int PSTR  = 136;
constexpr int PSTR2 = 72;

template <bool WSOUT>
__global__ void __launch_bounds__(256, 4)
attn_mfma_kernel(const float* __restrict__ qkv, float* __restrict__ out,
                 ushort* __restrict__ ws) {
  __shared__ ushort sK[128 * QSTR];    // 10240 B
  __shared__ ushort sVt[32 * PSTR];    //  8704 B
  __shared__ ushort sP[128 * PSTR2];   // 18432 B

  const int t    = threadIdx.x;
  const int bid  = xswz8(blockIdx.x, 2048);
  const int head = bid & 3;
  const int nw   = bid >> 2;
  const int wq   = nw & 31;
  const int d    = (nw >> 5) & 7;
  const int b    = nw >> 8;
  const int hc   = head * 24;

  const float* qpl = qkv + (size_t)(b * 8 + d) * HWC;
  const float* kpl = qpl + BDHWC;
  const float* vpl = kpl + BDHWC;
  ushort* wvpl = ws + BDHWC + (size_t)(b * 8 + d) * HWC;   // V bf16 out

  {
    const s16x8 Z = {0, 0, 0, 0, 0, 0, 0, 0};
    int row = t >> 1, col = 24 + (t & 1) * 8;
    *reinterpret_cast<s16x8*>(&sK[row * QSTR + col]) = Z;
    if (t < 136) *reinterpret_cast<s16x8*>(&sVt[24 * PSTR + t * 8]) = Z;
  }

  #pragma unroll
  for (int it = 0; it < 3; ++it) {
    int idx = t + it * 256;
    int tok = idx / 6, c4 = (idx - tok * 6) * 4;
    int g = (tok >> 1) * WC + (wq * 2 + (tok & 1)) * 96 + hc + c4;
    float4 kv = *reinterpret_cast<const float4*>(kpl + g);
    float4 vv = *reinterpret_cast<const float4*>(vpl + g);
    ushort4 kh = { f2bf(kv.x), f2bf(kv.y), f2bf(kv.z), f2bf(kv.w) };
    ushort4 vh = { f2bf(vv.x), f2bf(vv.y), f2bf(vv.z), f2bf(vv.w) };
    *reinterpret_cast<ushort4*>(&sK[tok * QSTR + c4]) = kh;
    sVt[(c4 + 0) * PSTR + tok] = vh.x;
    sVt[(c4 + 1) * PSTR + tok] = vh.y;
    sVt[(c4 + 2) * PSTR + tok] = vh.z;
    sVt[(c4 + 3) * PSTR + tok] = vh.w;
    if (WSOUT) *reinterpret_cast<ushort4*>(wvpl + g) = vh;   // V bf16 handoff
  }

  const int wv = t >> 6, lane = t & 63;
  const int lr = lane & 15;
  const int lg = lane >> 4;
  const int r0 = (2 * wv) * 16;
  const int r1 = (2 * wv + 1) * 16;

  s16x8 a0 = {0,0,0,0,0,0,0,0}, a1 = {0,0,0,0,0,0,0,0};
  if (lg < 3) {
    union { s16x8 v; ushort u[8]; } qa;
    int tok = r0 + lr;
    const float* qp = qpl + (tok >> 1) * WC + (wq * 2 + (tok & 1)) * 96 + hc + lg * 8;
    float4 x0 = *reinterpret_cast<const float4*>(qp);
    float4 x1 = *reinterpret_cast<const float4*>(qp + 4);
    qa.u[0] = f2bf(x0.x * SCALE); qa.u[1] = f2bf(x0.y * SCALE);
    qa.u[2] = f2bf(x0.z * SCALE); qa.u[3] = f2bf(x0.w * SCALE);
    qa.u[4] = f2bf(x1.x * SCALE); qa.u[5] = f2bf(x1.y * SCALE);
    qa.u[6] = f2bf(x1.z * SCALE); qa.u[7] = f2bf(x1.w * SCALE);
    a0 = qa.v;
    tok = r1 + lr;
    qp = qpl + (tok >> 1) * WC + (wq * 2 + (tok & 1)) * 96 + hc + lg * 8;
    x0 = *reinterpret_cast<const float4*>(qp);
    x1 = *reinterpret_cast<const float4*>(qp + 4);
    qa.u[0] = f2bf(x0.x * SCALE); qa.u[1] = f2bf(x0.y * SCALE);
    qa.u[2] = f2bf(x0.z * SCALE); qa.u[3] = f2bf(x0.w * SCALE);
    qa.u[4] = f2bf(x1.x * SCALE); qa.u[5] = f2bf(x1.y * SCALE);
    qa.u[6] = f2bf(x1.z * SCALE); qa.u[7] = f2bf(x1.w * SCALE);
    a1 = qa.v;
  }

  __syncthreads();

  float rsum[2][4];
  #pragma unroll
  for (int rb = 0; rb < 2; ++rb)
    #pragma unroll
    for (int r = 0; r < 4; ++r) rsum[rb][r] = 0.f;

  f32x4 accO[2][2];
  #pragma unroll
  for (int i = 0; i < 2; ++i)
    #pragma unroll
    for (int j = 0; j < 2; ++j) accO[i][j] = f32x4{0.f, 0.f, 0.f, 0.f};

  #pragma unroll
  for (int half = 0; half < 2; ++half) {
    f32x4 accS[2][4];
    #pragma unroll
    for (int i = 0; i < 2; ++i)
      #pragma unroll
      for (int j = 0; j < 4; ++j) accS[i][j] = f32x4{0.f, 0.f, 0.f, 0.f};

    #pragma unroll
    for (int nb = 0; nb < 4; ++nb) {
      s16x8 bb = *reinterpret_cast<const s16x8*>(
          &sK[(half * 64 + nb * 16 + lr) * QSTR + lg * 8]);
      accS[0][nb] = __builtin_amdgcn_mfma_f32_16x16x32_bf16(a0, bb, accS[0][nb], 0, 0, 0);
      accS[1][nb] = __builtin_amdgcn_mfma_f32_16x16x32_bf16(a1, bb, accS[1][nb], 0, 0, 0);
    }

    #pragma unroll
    for (int rb = 0; rb < 2; ++rb)
      #pragma unroll
      for (int nb = 0; nb < 4; ++nb)
        #pragma unroll
        for (int r = 0; r < 4; ++r) {
          float e = __expf(accS[rb][nb][r]);
          accS[rb][nb][r] = e;
          rsum[rb][r] += e;
        }

    if (half) __syncthreads();

    #pragma unroll
    for (int rb = 0; rb < 2; ++rb)
      #pragma unroll
      for (int nb = 0; nb < 4; ++nb)
        #pragma unroll
        for (int r = 0; r < 4; ++r)
          sP[((2 * wv + rb) * 16 + lg * 4 + r) * PSTR2 + nb * 16 + lr] =
              f2bf(accS[rb][nb][r]);
    __syncthreads();

    #pragma unroll
    for (int kb = 0; kb < 2; ++kb) {
      int kc = half * 64 + kb * 32 + lg * 8;
      s16x8 pa0 = *reinterpret_cast<const s16x8*>(&sP[(r0 + lr) * PSTR2 + kb * 32 + lg * 8]);
      s16x8 pa1 = *reinterpret_cast<const s16x8*>(&sP[(r1 + lr) * PSTR2 + kb * 32 + lg * 8]);
      s16x8 vb0 = *reinterpret_cast<const s16x8*>(&sVt[lr * PSTR + kc]);
      s16x8 vb1 = *reinterpret_cast<const s16x8*>(&sVt[(16 + lr) * PSTR + kc]);
      accO[0][0] = __builtin_amdgcn_mfma_f32_16x16x32_bf16(pa0, vb0, accO[0][0], 0, 0, 0);
      accO[0][1] = __builtin_amdgcn_mfma_f32_16x16x32_bf16(pa0, vb1, accO[0][1], 0, 0, 0);
      accO[1][0] = __builtin_amdgcn_mfma_f32_16x16x32_bf16(pa1, vb0, accO[1][0], 0, 0, 0);
      accO[1][1] = __builtin_amdgcn_mfma_f32_16x16x32_bf16(pa1, vb1, accO[1][1], 0, 0, 0);
    }
  }

  float* opl   = out + (size_t)(b * 8 + d) * HWC;
  ushort* wpl  = ws  + (size_t)(b * 8 + d) * HWC;
  #pragma unroll
  for (int rb = 0; rb < 2; ++rb) {
    #pragma unroll
    for (int r = 0; r < 4; ++r) {
      float s = rsum[rb][r];
      s += __shfl_xor(s, 1); s += __shfl_xor(s, 2);
      s += __shfl_xor(s, 4); s += __shfl_xor(s, 8);
      int tok = (2 * wv + rb) * 16 + lg * 4 + r;
      int g = (tok >> 1) * WC + (wq * 2 + (tok & 1)) * 96 + hc;
      float inv = 1.0f / s;
      if (WSOUT) {
        wpl[g + lr] = f2bf(accO[rb][0][r] * inv);
        if (lr < 8) wpl[g + 16 + lr] = f2bf(accO[rb][1][r] * inv);
      } else {
        opl[g + lr] = accO[rb][0][r] * inv;
        if (lr < 8) opl[g + 16 + lr] = accO[rb][1][r] * inv;
      }
    }
  }
}

// ====== Kernel CB: fused LePE + MFMA proj — r15 CFG + zero-halo V rows ======
// sV has 66 rows: row 0 and row 65 are permanent zeros (conv zero-pad).
// Staging writes V[w] -> sV[w+1]; taps read rows tt, tt+1, tt+2 with NO
// per-lane clamp/factor ops. CFG identical to r15 (continue-guarded regions).
constexpr int VSTR = 104;
constexpr int WSTR = 104;

template <bool WSIN>
__global__ void __launch_bounds__(256, 4)
lepe_proj_fused_kernel(const float* __restrict__ qkv, const float* __restrict__ cw,
                       const float* __restrict__ cbias, const float* __restrict__ pw,
                       const float* __restrict__ pb, float* __restrict__ io,
                       const ushort* __restrict__ ws) {
  __shared__ ushort sV[66 * VSTR];    // 13728 B (rows 0,65 = zero halo)
  __shared__ ushort sW[96 * WSTR];    // 19968 B
  __shared__ ushort sCW[27 * 96];     //  5184 B
  __shared__ float  sCB[96];
  __shared__ float  sPB[96];

  const int t   = threadIdx.x;
  const int bid = xswz8(blockIdx.x, 1024);
  const int h   = bid & 63;
  const int d   = (bid >> 6) & 7;
  const int b   = bid >> 9;

  float* iop = io + (size_t)(b * 8 + d) * HWC + h * WC;
  const ushort* wsp = ws + (size_t)(b * 8 + d) * HWC + h * WC;       // attn rows
  const ushort* wvb = ws + BDHWC + (size_t)b * 8 * HWC;              // V bf16 batch
  const float* vbatch = qkv + 2 * (size_t)BDHWC + (size_t)b * 8 * HWC;

  const int tt  = t >> 2;
  const int cbk = (t & 3) * 24;

  // ---- attn rows: issue reads first (in flight under weight staging) ----
  float lep[24];
  if (WSIN) {
    union { s16x8 v; ushort u[8]; } azu[3];
    #pragma unroll
    for (int k = 0; k < 3; ++k)
      azu[k].v = *reinterpret_cast<const s16x8*>(wsp + tt * 96 + cbk + k * 8);
    #pragma unroll
    for (int k = 0; k < 3; ++k)
      #pragma unroll
      for (int e = 0; e < 8; ++e) lep[8*k+e] = bf2f(azu[k].u[e]);
  } else {
    float4 az[6];
    #pragma unroll
    for (int j = 0; j < 6; ++j)
      az[j] = *reinterpret_cast<const float4*>(iop + tt * 96 + cbk + j * 4);
    #pragma unroll
    for (int j = 0; j < 6; ++j) {
      lep[4*j+0] = az[j].x; lep[4*j+1] = az[j].y;
      lep[4*j+2] = az[j].z; lep[4*j+3] = az[j].w;
    }
  }

  // ---- zero halo rows (once; visible after first region barrier) ----
  if (t < 26) {
    const s16x8 Z = {0, 0, 0, 0, 0, 0, 0, 0};
    int row = (t < 13) ? 0 : 65;
    int col = (t < 13 ? t : t - 13) * 8;
    *reinterpret_cast<s16x8*>(&sV[row * VSTR + col]) = Z;
  }

  // ---- stage weights ----
  #pragma unroll
  for (int it = 0; it < 9; ++it) {
    int idx = t + it * 256;
    int co = idx / 24, c4 = (idx - co * 24) * 4;
    float4 x = *reinterpret_cast<const float4*>(pw + co * 96 + c4);
    ushort4 hx = { f2bf(x.x), f2bf(x.y), f2bf(x.z), f2bf(x.w) };
    *reinterpret_cast<ushort4*>(&sW[co * WSTR + c4]) = hx;
  }
  for (int idx = t; idx < 2592; idx += 256) {
    int c = idx / 27, tap = idx - c * 27;
    sCW[tap * 96 + c] = f2bf(cw[idx]);
  }
  if (t < 96) { sCB[t] = cbias[t]; sPB[t] = pb[t]; }

  // halo-indexed taps: rows tt (left), tt+1 (center), tt+2 (right); no factors
  #define TAP(row, tap)                                                      \
    {                                                                        \
      _Pragma("unroll")                                                      \
      for (int j8 = 0; j8 < 3; ++j8) {                                       \
        union { s16x8 v; ushort u[8]; } vu;                                  \
        vu.v = *reinterpret_cast<const s16x8*>(&sV[(row) * VSTR + cbk + j8 * 8]); \
        union { s16x8 v; ushort u[8]; } wu;                                  \
        wu.v = *reinterpret_cast<const s16x8*>(&sCW[(tap) * 96 + cbk + j8 * 8]); \
        _Pragma("unroll")                                                    \
        for (int e = 0; e < 8; ++e)                                          \
          lep[8*j8+e] = fmaf(bf2f(vu.u[e]), bf2f(wu.u[e]), lep[8*j8+e]);     \
      }                                                                      \
    }

  #pragma unroll
  for (int dd = 0; dd < 3; ++dd) {
    int zd = d + dd - 1;
    if (zd < 0 || zd >= D_) continue;        // block-uniform
    #pragma unroll
    for (int dh = 0; dh < 3; ++dh) {
      int zh = h + dh - 1;
      if (zh < 0 || zh >= H_) continue;      // block-uniform
      __syncthreads();   // previous sV fully consumed
      if (WSIN) {
        // pure bf16 copy into rows 1..64: 768 u16x8 chunks
        const ushort* vrow = wvb + (size_t)zd * HWC + zh * WC;
        #pragma unroll
        for (int it = 0; it < 3; ++it) {
          int idx = t + it * 256;
          int tok = idx / 12, c8 = idx - tok * 12;
          s16x8 x = *reinterpret_cast<const s16x8*>(vrow + tok * 96 + c8 * 8);
          *reinterpret_cast<s16x8*>(&sV[(tok + 1) * VSTR + c8 * 8]) = x;
        }
      } else {
        const float4* src = reinterpret_cast<const float4*>(
            vbatch + (size_t)zd * HWC + zh * WC);
        #pragma unroll
        for (int it = 0; it < 6; ++it) {
          int idx = t + it * 256;
          int tok = idx / 24, c4 = idx - tok * 24;
          float4 x = src[idx];
          ushort4 hx = { f2bf(x.x), f2bf(x.y), f2bf(x.z), f2bf(x.w) };
          *reinterpret_cast<ushort4*>(&sV[(tok + 1) * VSTR + c4 * 4]) = hx;
        }
      }
      __syncthreads();
      const int tap0 = dd * 9 + dh * 3;
      TAP(tt,     tap0 + 0);
      TAP(tt + 1, tap0 + 1);
      TAP(tt + 2, tap0 + 2);
    }
  }
  #undef TAP

  // ---- sV dead: repack (lep + conv bias) bf16 as proj input (rows 0..63) ----
  __syncthreads();
  #pragma unroll
  for (int j = 0; j < 6; ++j) {
    float4 bz = *reinterpret_cast<const float4*>(sCB + cbk + j * 4);
    ushort4 hx = { f2bf(lep[4*j+0] + bz.x), f2bf(lep[4*j+1] + bz.y),
                   f2bf(lep[4*j+2] + bz.z), f2bf(lep[4*j+3] + bz.w) };
    *reinterpret_cast<ushort4*>(&sV[tt * VSTR + cbk + j * 4]) = hx;
  }
  __syncthreads();

  const int wv = t >> 6, lane = t & 63;
  const int lr = lane & 15, lg = lane >> 4;

  f32x4 acc[6];
  #pragma unroll
  for (int cb = 0; cb < 6; ++cb) {
    float bv = sPB[cb * 16 + lr];
    acc[cb] = f32x4{bv, bv, bv, bv};
  }
  s16x8 afr[3];
  #pragma unroll
  for (int kb = 0; kb < 3; ++kb)
    afr[kb] = *reinterpret_cast<const s16x8*>(&sV[(wv * 16 + lr) * VSTR + kb * 32 + lg * 8]);
  #pragma unroll
  for (int kb = 0; kb < 3; ++kb) {
    #pragma unroll
    for (int cb = 0; cb < 6; ++cb) {
      s16x8 bfr = *reinterpret_cast<const s16x8*>(&sW[(cb * 16 + lr) * WSTR + kb * 32 + lg * 8]);
      acc[cb] = __builtin_amdgcn_mfma_f32_16x16x32_bf16(afr[kb], bfr, acc[cb], 0, 0, 0);
    }
  }

  #pragma unroll
  for (int cb = 0; cb < 6; ++cb) {
    #pragma unroll
    for (int r = 0; r < 4; ++r) {
      int tok = wv * 16 + lg * 4 + r;
      iop[tok * 96 + cb * 16 + lr] = acc[cb][r];
    }
  }
}

extern "C" void kernel_launch(void* const* d_in, const int* in_sizes, int n_in,
                              void* d_out, int out_size, void* d_ws, size_t ws_size,
                              hipStream_t stream) {
  const float* qkv = (const float*)d_in[0];
  const float* cw  = (const float*)d_in[1];
  const float* cb  = (const float*)d_in[2];
  const float* pw  = (const float*)d_in[3];
  const float* pb  = (const float*)d_in[4];
  float* out = (float*)d_out;
  ushort* ws = (ushort*)d_ws;

  const size_t need = (size_t)2 * BDHWC * sizeof(ushort);  // 25.2 MB
  if (ws_size >= need) {
    hipLaunchKernelGGL((attn_mfma_kernel<true>), dim3(2048), dim3(256), 0, stream,
                       qkv, out, ws);
    hipLaunchKernelGGL((lepe_proj_fused_kernel<true>), dim3(1024), dim3(256), 0, stream,
                       qkv, cw, cb, pw, pb, out, ws);
  } else {
    hipLaunchKernelGGL((attn_mfma_kernel<false>), dim3(2048), dim3(256), 0, stream,
                       qkv, out, ws);
    hipLaunchKernelGGL((lepe_proj_fused_kernel<false>), dim3(1024), dim3(256), 0, stream,
                       qkv, cw, cb, pw, pb, out, ws);
  }
}